// Round 21
// baseline (240.404 us; speedup 1.0000x reference)
//
#include <hip/hip_runtime.h>
#include <math.h>

// TopKRouter: logits = rf @ gw^T, softmax, top-2, aux load-balance loss.
// rf: [16384, 4096] f32, gw: [64, 4096] f32.
// out (f32 flat): weights [0,32768) | indices-as-float [32768,65536) | aux [65536]
//
// R20: single-sweep fully-fused GEMM. No split-K: block = 32 rows x FULL
// K=4096 (128 steps), 256 thr (4 waves; wave = 16-expert block), grid 512 =
// 2 blocks/CU. R13 ring mechanics: 4-slot LDS ring (12 KB/slot: A 4K swz +
// W 8K), global_load_lds, depth-2 counted vmcnt(6) (3 loads/thread/step),
// bf16-split 3-term MFMA. W streamed from wsW (1 MB, L2-resident per XCD).
// rf swept ONCE per replay. Epilogue fused in-block (lt overlays drained
// ring; __syncthreads at transitions per R17 lesson). No partials, no
// epilogue kernel: 3 dispatches.
// ws: [0,256) psum | [256,512) cnt | [512,516) flagcnt | [768,+32K) flaglist
//     | [1M, +1MB) W frag stream.

typedef __attribute__((ext_vector_type(8))) short bf16x8;
typedef __attribute__((ext_vector_type(4))) float f32x4;

constexpr int B_ROWS  = 16384;
constexpr int D_DIM   = 4096;
constexpr int E_EXP   = 64;
constexpr int NTHR    = 512;    // wsplit threads
constexpr int GTHR    = 256;    // gemm threads (4 waves)
constexpr int TM      = 32;     // rows per block
constexpr int NS      = 128;    // K-steps (32 k each)
constexpr int SLOT    = 12288;  // ring slot: A 4K + W 8K
constexpr int FLAGCAP = 8192;
constexpr float GAPTHR = 1e-3f;

__device__ __forceinline__ float wave_max64(float v) {
#pragma unroll
  for (int m = 32; m >= 1; m >>= 1) v = fmaxf(v, __shfl_xor(v, m, 64));
  return v;
}
__device__ __forceinline__ float wave_sum64(float v) {
#pragma unroll
  for (int m = 32; m >= 1; m >>= 1) v += __shfl_xor(v, m, 64);
  return v;
}
// argmax over 64 lanes; ties -> smaller index (matches jax.lax.top_k)
__device__ __forceinline__ void wave_argmax64(float v, int i, float& mv, int& mi) {
#pragma unroll
  for (int m = 32; m >= 1; m >>= 1) {
    float ov = __shfl_xor(v, m, 64);
    int   oi = __shfl_xor(i, m, 64);
    if (ov > v || (ov == v && oi < i)) { v = ov; i = oi; }
  }
  mv = v; mi = i;
}

__device__ __forceinline__ void async_copy16(void* lds_dst, const void* g_src) {
  auto g = (const __attribute__((address_space(1))) char*)(g_src);
  auto l = (__attribute__((address_space(3))) char*)(lds_dst);
  __builtin_amdgcn_global_load_lds(g, l, 16, 0, 0);
}

// trunc-split 8 fp32 -> hi/lo bf16 frags (f = hi + rem exactly at bf16 precision)
__device__ __forceinline__ void split8(const f32x4 a, const f32x4 b, bf16x8& hi, bf16x8& lo) {
  float f[8] = {a[0], a[1], a[2], a[3], b[0], b[1], b[2], b[3]};
#pragma unroll
  for (int i = 0; i < 8; ++i) {
    unsigned int u = __float_as_uint(f[i]);
    hi[i] = (short)(u >> 16);
    float rem = f[i] - __uint_as_float(u & 0xffff0000u);
    lo[i] = (short)(__float_as_uint(rem) >> 16);
  }
}

// W pre-split: gw [64][4096] f32 -> frag stream [n=k/32][cb][h][lane][16B].
// B-frag (mfma_f32_16x16x32_bf16): lane l elem i <-> B[k=(l>>4)*8+i][col=l&15].
// Block 0 also zeroes the ws header (psum/cnt/flagcnt).
__global__ __launch_bounds__(NTHR) void wsplit(const float* __restrict__ gw,
                                               char* __restrict__ wsW,
                                               unsigned int* __restrict__ hdr) {
  const int n = blockIdx.x;          // 128 k-steps
  const int t = threadIdx.x;
  if (n == 0 && t < 192) hdr[t] = 0u;
  const int lane = t & 63, h = (t >> 6) & 1, wc = t >> 7;
  const int col = wc * 16 + (lane & 15);
  const int k0  = n * 32 + (lane >> 4) * 8;
  const float* src = gw + (size_t)col * D_DIM + k0;
  union { unsigned short us[8]; uint4 v; } pk;
#pragma unroll
  for (int i = 0; i < 8; ++i) {
    float f = src[i];
    unsigned int u = __float_as_uint(f);
    if (h == 0) {
      pk.us[i] = (unsigned short)(u >> 16);
    } else {
      float rem = f - __uint_as_float(u & 0xffff0000u);
      pk.us[i] = (unsigned short)(__float_as_uint(rem) >> 16);
    }
  }
  *(uint4*)(wsW + (size_t)n * 8192 + (size_t)t * 16) = pk.v;
}

__global__ __launch_bounds__(GTHR) void gemm_router(
    const float* __restrict__ rf, const char* __restrict__ wsW,
    float* __restrict__ out, float* __restrict__ psum,
    unsigned int* __restrict__ cnt, int* __restrict__ flagcnt,
    int* __restrict__ flaglist) {
  __shared__ char lds[4 * SLOT] __attribute__((aligned(16)));  // 48 KB ring
  __shared__ float pP[4][E_EXP];
  __shared__ unsigned int scnt[E_EXP];

  const int t = threadIdx.x, lane = t & 63, wv = t >> 6;  // wv = expert block cb
  const int row0 = blockIdx.x * TM;

  // A staging: tile [32 rows][8 x 16B slots]; LDS linear, source slot
  // pre-swizzled (s_glob = s_lds ^ (row&7)); 1 A-copy/thread.
  const int rowA = t >> 3, slA = t & 7;
  const int goffA = (row0 + rowA) * D_DIM + ((slA ^ (rowA & 7)) << 2);

  // compute-side A frag read offsets (rows lane&15 and +16; same low-3 bits)
  const int rr0 = lane & 15, rr1 = rr0 + 16;
  const int s0  = (lane >> 4) * 2;
  const int a00 = rr0 * 128 + ((s0 ^ (rr0 & 7)) << 4);
  const int a01 = rr0 * 128 + (((s0 + 1) ^ (rr0 & 7)) << 4);
  const int a10 = rr1 * 128 + ((s0 ^ (rr1 & 7)) << 4);
  const int a11 = rr1 * 128 + (((s0 + 1) ^ (rr1 & 7)) << 4);

  f32x4 acc0 = {0.f, 0.f, 0.f, 0.f}, acc1 = {0.f, 0.f, 0.f, 0.f};

#define ISSUE(nn)                                                            \
  {                                                                          \
    char* b_ = lds + ((nn) & 3) * SLOT;                                      \
    async_copy16(b_ + t * 16, rf + goffA + (nn) * 32);                       \
    async_copy16(b_ + 4096 + t * 16, wsW + (size_t)(nn) * 8192 + t * 16);    \
    async_copy16(b_ + 4096 + (GTHR + t) * 16,                                \
                 wsW + (size_t)(nn) * 8192 + (GTHR + t) * 16);               \
  }

#define STEP(nn)                                                             \
  {                                                                          \
    const char* ab = lds + ((nn) & 3) * SLOT;                                \
    const char* wb = ab + 4096 + wv * 2048 + lane * 16;                      \
    const f32x4 fl0 = *(const f32x4*)(ab + a00);                             \
    const f32x4 fh0 = *(const f32x4*)(ab + a01);                             \
    const f32x4 fl1 = *(const f32x4*)(ab + a10);                             \
    const f32x4 fh1 = *(const f32x4*)(ab + a11);                             \
    bf16x8 ahi0, alo0, ahi1, alo1;                                           \
    split8(fl0, fh0, ahi0, alo0);                                            \
    split8(fl1, fh1, ahi1, alo1);                                            \
    const bf16x8 whi = *(const bf16x8*)(wb);                                 \
    const bf16x8 wlo = *(const bf16x8*)(wb + 1024);                          \
    acc0 = __builtin_amdgcn_mfma_f32_16x16x32_bf16(ahi0, whi, acc0, 0, 0, 0);\
    acc0 = __builtin_amdgcn_mfma_f32_16x16x32_bf16(alo0, whi, acc0, 0, 0, 0);\
    acc0 = __builtin_amdgcn_mfma_f32_16x16x32_bf16(ahi0, wlo, acc0, 0, 0, 0);\
    acc1 = __builtin_amdgcn_mfma_f32_16x16x32_bf16(ahi1, whi, acc1, 0, 0, 0);\
    acc1 = __builtin_amdgcn_mfma_f32_16x16x32_bf16(alo1, whi, acc1, 0, 0, 0);\
    acc1 = __builtin_amdgcn_mfma_f32_16x16x32_bf16(ahi1, wlo, acc1, 0, 0, 0);\
  }

  ISSUE(0);
  ISSUE(1);
#pragma unroll 2
  for (int n = 0; n < NS - 2; ++n) {
    ISSUE(n + 2);                                     // depth-2 lookahead
    asm volatile("s_waitcnt vmcnt(6)" ::: "memory");  // tile n resident (mine)
    __builtin_amdgcn_s_barrier();                     // tile n resident (all)
    STEP(n);
    __builtin_amdgcn_s_barrier();                     // ring slot n&3 free
  }
  asm volatile("s_waitcnt vmcnt(3)" ::: "memory");
  __builtin_amdgcn_s_barrier();
  STEP(NS - 2);
  __builtin_amdgcn_s_barrier();
  asm volatile("s_waitcnt vmcnt(0)" ::: "memory");
  __builtin_amdgcn_s_barrier();
  STEP(NS - 1);
#undef ISSUE
#undef STEP

  // ---- fused epilogue: lt overlays the drained ring ----
  __syncthreads();                       // full drain (lgkm+vm) + rendezvous
  float* lt = (float*)lds;               // [32][65]
  if (t < E_EXP) scnt[t] = 0;
  {
    const int colb = wv * 16 + (lane & 15);
    const int rowb = (lane >> 4) * 4;
#pragma unroll
    for (int j = 0; j < 4; ++j) {
      lt[(rowb + j) * 65 + colb] = acc0[j];
      lt[(rowb + 16 + j) * 65 + colb] = acc1[j];
    }
  }
  __syncthreads();

  // wave wv handles rows wv*8 .. +8; lane = expert
  float Pacc = 0.f;
#pragma unroll
  for (int jr = 0; jr < 8; ++jr) {
    const int r = wv * 8 + jr;
    const float lg = lt[r * 65 + lane];
    const float mx = wave_max64(lg);
    const float pe = __expf(lg - mx);
    const float ss = wave_sum64(pe);
    Pacc += pe / ss;
    float v1; int i1; wave_argmax64(lg, lane, v1, i1);
    const float lm1 = (lane == i1) ? -INFINITY : lg;
    float v2; int i2; wave_argmax64(lm1, lane, v2, i2);
    const float lm2 = (lane == i2) ? -INFINITY : lm1;
    float v3; int i3; wave_argmax64(lm2, lane, v3, i3);
    if (lane == 0) {
      const float ex = expf(v2 - v1);
      const int row = row0 + r;
      out[row * 2 + 0] = 1.f / (1.f + ex);
      out[row * 2 + 1] = ex / (1.f + ex);
      out[2 * B_ROWS + row * 2 + 0] = (float)i1;
      out[2 * B_ROWS + row * 2 + 1] = (float)i2;
      atomicAdd(&scnt[i1], 1u);
      atomicAdd(&scnt[i2], 1u);
      if (v1 - v2 < GAPTHR || v2 - v3 < GAPTHR) {
        int fi = atomicAdd(flagcnt, 1);
        if (fi < FLAGCAP) flaglist[fi] = row;
      }
    }
  }
  pP[wv][lane] = Pacc;
  __syncthreads();
  if (t < E_EXP) {
    atomicAdd(&psum[t], pP[0][t] + pP[1][t] + pP[2][t] + pP[3][t]);
    const unsigned int c = scnt[t];
    if (c) atomicAdd(&cnt[t], c);
  }
}

// exact fp64 recompute of flagged (near-tie) rows; block 0 also computes aux.
__global__ __launch_bounds__(256) void cleanup(
    const float* __restrict__ rf, const float* __restrict__ gw,
    const int* __restrict__ flagcnt, const int* __restrict__ flaglist,
    const float* __restrict__ psum, const unsigned int* __restrict__ cnt,
    float* __restrict__ out) {
  __shared__ double sm[256];
  const int t = threadIdx.x;
  if (blockIdx.x == 0 && t < 64) {
    const float f = (float)cnt[t] / (float)(B_ROWS * 2);
    const float P = psum[t] / (float)B_ROWS;
    float v = wave_sum64(f * P);
    if (t == 0) out[4 * B_ROWS] = (float)E_EXP * v;
  }
  const int nf = min(*flagcnt, FLAGCAP);
  for (int fi = blockIdx.x; fi < nf; fi += gridDim.x) {
    const int row = flaglist[fi];
    const int e = t & 63, seg = t >> 6;
    const float* a = rf + (size_t)row * D_DIM + seg * 1024;
    const float* w = gw + (size_t)e * D_DIM + seg * 1024;
    double p0 = 0.0, p1 = 0.0, p2 = 0.0, p3 = 0.0;
    for (int k = 0; k < 1024; k += 4) {
      p0 = fma((double)a[k + 0], (double)w[k + 0], p0);
      p1 = fma((double)a[k + 1], (double)w[k + 1], p1);
      p2 = fma((double)a[k + 2], (double)w[k + 2], p2);
      p3 = fma((double)a[k + 3], (double)w[k + 3], p3);
    }
    sm[t] = (p0 + p1) + (p2 + p3);
    __syncthreads();
    if (t < 64) {
      const double l = sm[t] + sm[64 + t] + sm[128 + t] + sm[192 + t];
      double v = l; int ii = t;
#pragma unroll
      for (int m = 32; m >= 1; m >>= 1) {
        double ov = __shfl_xor(v, m, 64); int oi = __shfl_xor(ii, m, 64);
        if (ov > v || (ov == v && oi < ii)) { v = ov; ii = oi; }
      }
      const double v1 = v; const int i1 = ii;
      const double lm = (t == i1) ? -1e300 : l;
      v = lm; ii = t;
#pragma unroll
      for (int m = 32; m >= 1; m >>= 1) {
        double ov = __shfl_xor(v, m, 64); int oi = __shfl_xor(ii, m, 64);
        if (ov > v || (ov == v && oi < ii)) { v = ov; ii = oi; }
      }
      const double v2 = v; const int i2 = ii;
      if (t == 0) {
        const double ex = exp(v2 - v1);
        out[row * 2 + 0] = (float)(1.0 / (1.0 + ex));
        out[row * 2 + 1] = (float)(ex / (1.0 + ex));
        out[2 * B_ROWS + row * 2 + 0] = (float)i1;
        out[2 * B_ROWS + row * 2 + 1] = (float)i2;
      }
    }
    __syncthreads();
  }
}

extern "C" void kernel_launch(void* const* d_in, const int* in_sizes, int n_in,
                              void* d_out, int out_size, void* d_ws, size_t ws_size,
                              hipStream_t stream) {
  const float* rf = (const float*)d_in[0];
  const float* gw = (const float*)d_in[1];
  float* out = (float*)d_out;
  float* psum = (float*)d_ws;
  unsigned int* cnt = (unsigned int*)((char*)d_ws + 256);
  int* flagcnt = (int*)((char*)d_ws + 512);
  int* flaglist = (int*)((char*)d_ws + 768);
  char* wsW = (char*)d_ws + (1u << 20);

  wsplit<<<D_DIM / 32, NTHR, 0, stream>>>(gw, wsW, (unsigned int*)d_ws);
  gemm_router<<<B_ROWS / TM, GTHR, 0, stream>>>(rf, wsW, out, psum, cnt,
                                                flagcnt, flaglist);
  cleanup<<<64, 256, 0, stream>>>(rf, gw, flagcnt, flaglist, psum, cnt, out);
}